// Round 2
// baseline (7491.363 us; speedup 1.0000x reference)
//
#include <hip/hip_runtime.h>
#include <hip/hip_bf16.h>
#include <cstdint>

typedef unsigned short ushort_t;
typedef __attribute__((ext_vector_type(8))) short short8;
typedef __attribute__((ext_vector_type(4))) float floatx4;
typedef __attribute__((ext_vector_type(4))) ushort_t ushort4v;

#define DEVI __device__ __forceinline__

DEVI float b2f(ushort_t u){ union{unsigned int i; float f;} v; v.i = ((unsigned int)u)<<16; return v.f; }
DEVI ushort_t f2b(float f){ union{float f; unsigned int i;} v; v.f=f; unsigned int r = (v.i + 0x7FFFu + ((v.i>>16)&1u)) >> 16; return (ushort_t)r; }

DEVI float gelu_f(float t){
  float t3 = t*t*t;
  return 0.5f*t*(1.0f + tanhf(0.7978845608028654f*(t + 0.044715f*t3)));
}

#define GLD_LDS16(src, dst) \
  __builtin_amdgcn_global_load_lds((const __attribute__((address_space(1))) void*)(src), \
                                   (__attribute__((address_space(3))) void*)(dst), 16, 0, 0)

// out[M,N](bf16) = epi(A[M,K](bf16) @ Bt[N,K]^T + bias(fp32) [, res(fp32)])
// EPI: 0 = elu(v)+1, 1 = v, 2 = gelu(v), 3 = gelu(v)+res
template<int EPI>
__global__ __launch_bounds__(256)
void gemm_kernel(const ushort_t* __restrict__ A, const ushort_t* __restrict__ Bt,
                 const float* __restrict__ bias, const float* __restrict__ res,
                 ushort_t* __restrict__ out, int N, int K)
{
  __shared__ alignas(16) ushort_t As[128*32];
  __shared__ alignas(16) ushort_t Bs[128*32];
  const int tid  = threadIdx.x;
  const int wave = tid >> 6, lane = tid & 63;
  const int quad = lane >> 4, l16 = lane & 15;
  const int tileM = blockIdx.x * 128, tileN = blockIdx.y * 128;
  const int wm = (wave >> 1) * 64, wn = (wave & 1) * 64;

  floatx4 acc[4][4] = {};

  const int c0 = tid, c1 = 256 + tid;   // 16B chunks: row = c>>2, k-off = (c&3)*8
  const size_t aoff0 = (size_t)(tileM + (c0 >> 2)) * K + (c0 & 3) * 8;
  const size_t aoff1 = (size_t)(tileM + (c1 >> 2)) * K + (c1 & 3) * 8;
  const size_t boff0 = (size_t)(tileN + (c0 >> 2)) * K + (c0 & 3) * 8;
  const size_t boff1 = (size_t)(tileN + (c1 >> 2)) * K + (c1 & 3) * 8;

  for (int k0 = 0; k0 < K; k0 += 32){
    __syncthreads();
    GLD_LDS16(A  + aoff0 + k0, As + wave*512);
    GLD_LDS16(A  + aoff1 + k0, As + 2048 + wave*512);
    GLD_LDS16(Bt + boff0 + k0, Bs + wave*512);
    GLD_LDS16(Bt + boff1 + k0, Bs + 2048 + wave*512);
    __syncthreads();

    short8 af[4], bfv[4];
    #pragma unroll
    for (int i = 0; i < 4; i++){
      af[i]  = *(const short8*)(As + (wm + i*16 + l16)*32 + quad*8);
      bfv[i] = *(const short8*)(Bs + (wn + i*16 + l16)*32 + quad*8);
    }
    #pragma unroll
    for (int mi = 0; mi < 4; mi++)
      #pragma unroll
      for (int ni = 0; ni < 4; ni++)
        acc[mi][ni] = __builtin_amdgcn_mfma_f32_16x16x32_bf16(af[mi], bfv[ni], acc[mi][ni], 0, 0, 0);
  }

  float bv4[4];
  #pragma unroll
  for (int ni = 0; ni < 4; ni++) bv4[ni] = bias[tileN + wn + ni*16 + l16];

  #pragma unroll
  for (int mi = 0; mi < 4; mi++){
    #pragma unroll
    for (int r = 0; r < 4; r++){
      const int row = tileM + wm + mi*16 + quad*4 + r;
      #pragma unroll
      for (int ni = 0; ni < 4; ni++){
        const int col = tileN + wn + ni*16 + l16;
        float v = acc[mi][ni][r] + bv4[ni];
        if constexpr (EPI == 0){ v = (v > 0.f) ? (v + 1.f) : expf(v); }
        else if constexpr (EPI == 2){ v = gelu_f(v); }
        else if constexpr (EPI == 3){ v = gelu_f(v) + res[(size_t)row*N + col]; }
        out[(size_t)row*N + col] = f2b(v);
      }
    }
  }
}

// KV[b,h] = sum_s K[b,s,h]*V[b,s,h]; Ksum[b,h] = sum_s K[b,s,h]   (bf16 in, fp32 atomics)
__global__ __launch_bounds__(256)
void reduce_kv_kernel(const ushort_t* __restrict__ Kb, const ushort_t* __restrict__ Vb,
                      float* __restrict__ KV, float* __restrict__ Ksum)
{
  const int b = blockIdx.x >> 6, chunk = blockIdx.x & 63;
  const int t = threadIdx.x;
  const size_t base = ((size_t)b*4096 + (size_t)chunk*64)*1024 + t*4;
  float kv[4] = {0,0,0,0}, ks[4] = {0,0,0,0};
  for (int s = 0; s < 64; s++){
    ushort4v kk = *(const ushort4v*)(Kb + base + (size_t)s*1024);
    ushort4v vv = *(const ushort4v*)(Vb + base + (size_t)s*1024);
    #pragma unroll
    for (int j = 0; j < 4; j++){ float kf = b2f(kk[j]); kv[j] += kf*b2f(vv[j]); ks[j] += kf; }
  }
  #pragma unroll
  for (int j = 0; j < 4; j++){
    atomicAdd(&KV[b*1024 + t*4 + j], kv[j]);
    atomicAdd(&Ksum[b*1024 + t*4 + j], ks[j]);
  }
}

// Q <- Q*KV / (Q*Ksum + eps), in place (bf16)
__global__ __launch_bounds__(256)
void attn_map_kernel(ushort_t* __restrict__ Q, const float* __restrict__ KV, const float* __restrict__ Ksum)
{
  const size_t g = (size_t)blockIdx.x*256 + threadIdx.x;
  const size_t base = g*4;
  const int b  = (int)(base >> 22);     // 4096*1024 = 2^22 elements per batch
  const int h0 = (int)(base & 1023);
  ushort4v q4 = *(const ushort4v*)(Q + base);
  ushort4v o4;
  #pragma unroll
  for (int j = 0; j < 4; j++){
    float q = b2f(q4[j]);
    float v = q*KV[b*1024 + h0 + j] / (q*Ksum[b*1024 + h0 + j] + 1e-6f);
    o4[j] = f2b(v);
  }
  *(ushort4v*)(Q + base) = o4;
}

// LayerNorm over rows of 1024: y(bf16) -> xb(bf16) AND xf(fp32)
__global__ __launch_bounds__(256)
void ln_kernel(const ushort_t* __restrict__ y, const float* __restrict__ sc,
               const float* __restrict__ bi, ushort_t* __restrict__ xb, float* __restrict__ xf)
{
  const int row = blockIdx.x, t = threadIdx.x;
  const ushort_t* yr = y + (size_t)row*1024;
  ushort4v v4 = *(const ushort4v*)(yr + t*4);
  float f[4]; float s1 = 0.f, s2 = 0.f;
  #pragma unroll
  for (int j = 0; j < 4; j++){ f[j] = b2f(v4[j]); s1 += f[j]; s2 += f[j]*f[j]; }
  #pragma unroll
  for (int off = 32; off; off >>= 1){ s1 += __shfl_down(s1, off); s2 += __shfl_down(s2, off); }
  __shared__ float red[2][4];
  const int wave = t >> 6, lane = t & 63;
  if (lane == 0){ red[0][wave] = s1; red[1][wave] = s2; }
  __syncthreads();
  s1 = red[0][0] + red[0][1] + red[0][2] + red[0][3];
  s2 = red[1][0] + red[1][1] + red[1][2] + red[1][3];
  const float mean = s1 * (1.0f/1024.0f);
  const float var  = s2 * (1.0f/1024.0f) - mean*mean;
  const float inv  = rsqrtf(var + 1e-6f);
  ushort4v o4;
  #pragma unroll
  for (int j = 0; j < 4; j++){
    const int h = t*4 + j;
    const float o = (f[j] - mean)*inv*sc[h] + bi[h];
    o4[j] = f2b(o);
    xf[(size_t)row*1024 + h] = o;
  }
  *(ushort4v*)(xb + (size_t)row*1024 + t*4) = o4;
}

// out[C,R](bf16) = in[R,C]^T (fp32 in)
__global__ __launch_bounds__(256)
void transpose_cvt_kernel(const float* __restrict__ in, ushort_t* __restrict__ out, int R, int C)
{
  __shared__ float tile[32][33];
  const int t = threadIdx.x;
  const int tx = t & 31, ty = t >> 5;
  const int rb = blockIdx.y*32, cb = blockIdx.x*32;
  #pragma unroll
  for (int j = 0; j < 32; j += 8) tile[ty+j][tx] = in[(size_t)(rb+ty+j)*C + cb+tx];
  __syncthreads();
  #pragma unroll
  for (int j = 0; j < 32; j += 8) out[(size_t)(cb+ty+j)*R + rb+tx] = f2b(tile[tx][ty+j]);
}

// bf16 copy of fp32 input
__global__ __launch_bounds__(256)
void cvt_kernel(const float* __restrict__ in, ushort_t* __restrict__ out)
{
  const size_t base = ((size_t)blockIdx.x*256 + threadIdx.x)*4;
  ushort4v o4;
  #pragma unroll
  for (int j = 0; j < 4; j++) o4[j] = f2b(in[base + j]);
  *(ushort4v*)(out + base) = o4;
}

extern "C" void kernel_launch(void* const* d_in, const int* in_sizes, int n_in,
                              void* d_out, int out_size, void* d_ws, size_t ws_size,
                              hipStream_t stream)
{
  const float* x_in = (const float*)d_in[0];
  const float* Wq   = (const float*)d_in[1];
  const float* bq   = (const float*)d_in[2];
  const float* Wk   = (const float*)d_in[3];
  const float* bk   = (const float*)d_in[4];
  const float* Wv   = (const float*)d_in[5];
  const float* bv   = (const float*)d_in[6];
  const float* Wo   = (const float*)d_in[7];
  const float* bo   = (const float*)d_in[8];
  const float* ln1s = (const float*)d_in[9];
  const float* ln1b = (const float*)d_in[10];
  const float* W1   = (const float*)d_in[11];
  const float* b1   = (const float*)d_in[12];
  const float* W2   = (const float*)d_in[13];
  const float* b2   = (const float*)d_in[14];
  const float* ln2s = (const float*)d_in[15];
  const float* ln2b = (const float*)d_in[16];

  float* xf = (float*)d_out;            // fp32 master activation (also final output)

  char* ws = (char*)d_ws;
  const size_t MB = 1024*1024;
  ushort_t* xb     = (ushort_t*)(ws);            // 32MB bf16 activation
  ushort_t* bufQ   = (ushort_t*)(ws + 32*MB);    // 32MB Q -> V_attn
  ushort_t* bufK   = (ushort_t*)(ws + 64*MB);    // 32MB K
  ushort_t* bufVal = (ushort_t*)(ws + 96*MB);    // 32MB value, then pre-LN y
  ushort_t* bufH   = (ushort_t*)(ws + 128*MB);   // 64MB FF hidden (half M)
  ushort_t* WqT    = (ushort_t*)(ws + 192*MB);   // 2MB each
  ushort_t* WkT    = (ushort_t*)(ws + 194*MB);
  ushort_t* WvT    = (ushort_t*)(ws + 196*MB);
  ushort_t* WoT    = (ushort_t*)(ws + 198*MB);
  ushort_t* W1T    = (ushort_t*)(ws + 200*MB);   // 8MB
  ushort_t* W2T    = (ushort_t*)(ws + 208*MB);   // 8MB
  float*    KV     = (float*)(ws + 216*MB);      // 16KB
  float*    Ksum   = (float*)(ws + 216*MB + 16*1024);

  const int M = 16384, D = 1024, FF = 4096;
  const dim3 blk(256);

  hipMemcpyAsync(xf, x_in, (size_t)M*D*sizeof(float), hipMemcpyDeviceToDevice, stream);
  cvt_kernel<<<dim3(M*D/1024), blk, 0, stream>>>(x_in, xb);

  for (int i = 0; i < 8; i++){
    transpose_cvt_kernel<<<dim3(32, 32),  blk, 0, stream>>>(Wq + (size_t)i*D*D,  WqT, D, D);
    transpose_cvt_kernel<<<dim3(32, 32),  blk, 0, stream>>>(Wk + (size_t)i*D*D,  WkT, D, D);
    transpose_cvt_kernel<<<dim3(32, 32),  blk, 0, stream>>>(Wv + (size_t)i*D*D,  WvT, D, D);
    transpose_cvt_kernel<<<dim3(32, 32),  blk, 0, stream>>>(Wo + (size_t)i*D*D,  WoT, D, D);
    transpose_cvt_kernel<<<dim3(128, 32), blk, 0, stream>>>(W1 + (size_t)i*D*FF, W1T, D, FF);
    transpose_cvt_kernel<<<dim3(32, 128), blk, 0, stream>>>(W2 + (size_t)i*FF*D, W2T, FF, D);

    // Q = elu(x@Wq + bq)+1 ; K = elu(x@Wk + bk)+1 ; value = x@Wv + bv
    gemm_kernel<0><<<dim3(128, 8), blk, 0, stream>>>(xb, WqT, bq + i*D, nullptr, bufQ, D, D);
    gemm_kernel<0><<<dim3(128, 8), blk, 0, stream>>>(xb, WkT, bk + i*D, nullptr, bufK, D, D);
    gemm_kernel<1><<<dim3(128, 8), blk, 0, stream>>>(xb, WvT, bv + i*D, nullptr, bufVal, D, D);

    hipMemsetAsync(KV, 0, 32*1024, stream);
    reduce_kv_kernel<<<dim3(256), blk, 0, stream>>>(bufK, bufVal, KV, Ksum);
    attn_map_kernel<<<dim3(16384), blk, 0, stream>>>(bufQ, KV, Ksum);

    // y = gelu(V_attn@Wo + bo) + x ; x = LN1(y)
    gemm_kernel<3><<<dim3(128, 8), blk, 0, stream>>>(bufQ, WoT, bo + i*D, xf, bufVal, D, D);
    ln_kernel<<<dim3(16384), blk, 0, stream>>>(bufVal, ln1s + i*D, ln1b + i*D, xb, xf);

    // h = gelu(x@W1 + b1) ; y = gelu(h@W2 + b2) + x ; x = LN2(y)  — two M-halves to bound ws
    for (int h = 0; h < 2; h++){
      const size_t m0 = (size_t)h * 8192;
      gemm_kernel<2><<<dim3(64, 32), blk, 0, stream>>>(xb + m0*D, W1T, b1 + i*FF, nullptr, bufH, FF, D);
      gemm_kernel<3><<<dim3(64, 8),  blk, 0, stream>>>(bufH, W2T, b2 + i*D, xf + m0*D, bufVal + m0*D, D, FF);
    }
    ln_kernel<<<dim3(16384), blk, 0, stream>>>(bufVal, ln2s + i*D, ln2b + i*D, xb, xf);
  }
  (void)in_sizes; (void)n_in; (void)out_size; (void)ws_size;
}